// Round 2
// baseline (1907.419 us; speedup 1.0000x reference)
//
#include <hip/hip_runtime.h>
#include <math.h>

#define NN 100000
#define NE 1600000
#define F 128      // node feat dim (in == out)
#define EF 64      // edge feat dim
#define NH 4       // heads
#define HD 32      // head dim

// ---------------------------------------------------------------------------
// K0: c[h][j] = sum_d W_proj[h*32+d][128+j] * av[h][d]   (4x64, one block)
// ---------------------------------------------------------------------------
__global__ void k_prep_c(const float* __restrict__ Wp, const float* __restrict__ av,
                         float* __restrict__ c) {
    int t = threadIdx.x;          // 256 threads = 4 heads x 64 j
    int h = t >> 6;
    int j = t & 63;
    float acc = 0.f;
#pragma unroll
    for (int d = 0; d < HD; ++d)
        acc += Wp[(h * HD + d) * 192 + 128 + j] * av[h * HD + d];
    c[h * EF + j] = acc;
}

// ---------------------------------------------------------------------------
// K1: P[n][k] = bias[k] + sum_{j<128} nfeats[n][j] * Wp[k][j]
// block=256, 32 nodes/block, W staged in halves (64 rows) to keep LDS < 50KB
// ---------------------------------------------------------------------------
__global__ __launch_bounds__(256, 3) void k_node_proj(
    const float* __restrict__ nf, const float* __restrict__ Wp,
    const float* __restrict__ bp, float* __restrict__ P) {
    __shared__ float in_t[32][129];
    __shared__ float w_t[64][129];
    int t = threadIdx.x;
    int nb = blockIdx.x * 32;
    // load 32x128 input tile (1024 float4, 4 per thread), coalesced
#pragma unroll
    for (int i = 0; i < 4; ++i) {
        int f4 = i * 256 + t;
        int row = f4 >> 5, c4 = f4 & 31;
        float4 v = ((const float4*)(nf + (size_t)(nb + row) * F))[c4];
        in_t[row][c4 * 4 + 0] = v.x; in_t[row][c4 * 4 + 1] = v.y;
        in_t[row][c4 * 4 + 2] = v.z; in_t[row][c4 * 4 + 3] = v.w;
    }
    int kk = t & 63, ng = t >> 6;
    for (int kh = 0; kh < 2; ++kh) {
        __syncthreads();
        // stage W rows [kh*64, kh*64+64), cols 0..127 (row stride 192)
#pragma unroll
        for (int i = 0; i < 8; ++i) {
            int f4 = i * 256 + t;
            int row = f4 >> 5, c4 = f4 & 31;
            float4 v = *(const float4*)(Wp + (size_t)(kh * 64 + row) * 192 + c4 * 4);
            w_t[row][c4 * 4 + 0] = v.x; w_t[row][c4 * 4 + 1] = v.y;
            w_t[row][c4 * 4 + 2] = v.z; w_t[row][c4 * 4 + 3] = v.w;
        }
        __syncthreads();
        float acc[8] = {0.f, 0.f, 0.f, 0.f, 0.f, 0.f, 0.f, 0.f};
        for (int j = 0; j < 128; ++j) {
            float w = w_t[kk][j];          // 2-way (free) bank pattern
#pragma unroll
            for (int i = 0; i < 8; ++i)
                acc[i] += in_t[ng * 8 + i][j] * w;   // broadcast
        }
        float b = bp[kh * 64 + kk];
#pragma unroll
        for (int i = 0; i < 8; ++i)
            P[(size_t)(nb + ng * 8 + i) * F + kh * 64 + kk] = acc[i] + b;
    }
}

// ---------------------------------------------------------------------------
// K1b: sn[n][h] = sum_d P[n][h*32+d] * av[h][d]
// ---------------------------------------------------------------------------
__global__ void k_sn(const float* __restrict__ P, const float* __restrict__ av,
                     float* __restrict__ sn) {
    __shared__ __align__(16) float avs[128];
    int t = threadIdx.x;
    if (t < 128) avs[t] = av[t];
    __syncthreads();
    int n = blockIdx.x * 64 + (t >> 2);
    int h = t & 3;
    if (n >= NN) return;
    const float* p = P + (size_t)n * F + h * HD;
    const float* a = avs + h * HD;
    float acc = 0.f;
#pragma unroll
    for (int q = 0; q < 8; ++q) {
        float4 v = ((const float4*)p)[q];
        float4 w = ((const float4*)a)[q];
        acc += v.x * w.x + v.y * w.y + v.z * w.z + v.w * w.w;
    }
    sn[n * 4 + h] = acc;
}

// ---------------------------------------------------------------------------
// K2: per edge: score e[h] = sn[src] + efeats . c[h]; ex = exp(e);
//     atomicAdd denom[dst]. No segment-max needed (|e| <~ 10, fp32-safe).
// ---------------------------------------------------------------------------
__global__ __launch_bounds__(256, 2) void k_edge_score(
    const float* __restrict__ ef, const int* __restrict__ src,
    const int* __restrict__ dst, const float* __restrict__ sn,
    const float* __restrict__ c, float* __restrict__ ex,
    float* __restrict__ denom) {
    __shared__ float eft[256][65];
    __shared__ float cs[4][64];
    int t = threadIdx.x;
    int eb = blockIdx.x * 256;
    cs[t >> 6][t & 63] = c[t];
    // stage 256 edges x 64 floats, coalesced (4096 float4, 16/thread)
#pragma unroll
    for (int i = 0; i < 16; ++i) {
        int f4 = i * 256 + t;
        int row = f4 >> 4, c4 = f4 & 15;
        float4 v = ((const float4*)(ef + (size_t)(eb + row) * EF))[c4];
        eft[row][c4 * 4 + 0] = v.x; eft[row][c4 * 4 + 1] = v.y;
        eft[row][c4 * 4 + 2] = v.z; eft[row][c4 * 4 + 3] = v.w;
    }
    __syncthreads();
    int e = eb + t;
    int s = src[e], d = dst[e];
    float4 snv = *(const float4*)(sn + (size_t)s * 4);
    float a0 = snv.x, a1 = snv.y, a2 = snv.z, a3 = snv.w;
    for (int j = 0; j < 64; ++j) {
        float x = eft[t][j];               // (t+j)%32: conflict-free
        a0 += x * cs[0][j];
        a1 += x * cs[1][j];
        a2 += x * cs[2][j];
        a3 += x * cs[3][j];
    }
    float e0 = __expf(a0), e1 = __expf(a1), e2 = __expf(a2), e3 = __expf(a3);
    float4 exv = make_float4(e0, e1, e2, e3);
    *(float4*)(ex + (size_t)e * 4) = exv;
    atomicAdd(&denom[d * 4 + 0], e0);
    atomicAdd(&denom[d * 4 + 1], e1);
    atomicAdd(&denom[d * 4 + 2], e2);
    atomicAdd(&denom[d * 4 + 3], e3);
}

// ---------------------------------------------------------------------------
// K3: per edge: Q = efeats @ We.T (register-tiled from LDS);
//     m = alpha * (P[src] + Q); atomicAdd into hne[dst].
// block=256, 64 edges/block. Thread tile: 4 edges x 8 k (k strided by 16).
// ---------------------------------------------------------------------------
__global__ __launch_bounds__(256, 3) void k_edge_msg(
    const float* __restrict__ ef, const int* __restrict__ src,
    const int* __restrict__ dst, const float* __restrict__ Wp,
    const float* __restrict__ P, const float* __restrict__ ex,
    const float* __restrict__ denom, float* __restrict__ hne) {
    __shared__ float eft[64][65];    // 16.6 KB
    __shared__ float wt[128][65];    // 33.3 KB  (We[k][j] = Wp[k*192+128+j])
    int t = threadIdx.x;
    int eb = blockIdx.x * 64;
    // stage We (128x64): 2048 float4, 8/thread
#pragma unroll
    for (int i = 0; i < 8; ++i) {
        int f4 = i * 256 + t;
        int row = f4 >> 4, c4 = f4 & 15;
        float4 v = *(const float4*)(Wp + (size_t)row * 192 + 128 + c4 * 4);
        wt[row][c4 * 4 + 0] = v.x; wt[row][c4 * 4 + 1] = v.y;
        wt[row][c4 * 4 + 2] = v.z; wt[row][c4 * 4 + 3] = v.w;
    }
    // stage efeats (64x64): 1024 float4, 4/thread
#pragma unroll
    for (int i = 0; i < 4; ++i) {
        int f4 = i * 256 + t;
        int row = f4 >> 4, c4 = f4 & 15;
        float4 v = ((const float4*)(ef + (size_t)(eb + row) * EF))[c4];
        eft[row][c4 * 4 + 0] = v.x; eft[row][c4 * 4 + 1] = v.y;
        eft[row][c4 * 4 + 2] = v.z; eft[row][c4 * 4 + 3] = v.w;
    }
    __syncthreads();
    int et = t >> 4;      // edge group 0..15 (uniform per 16 lanes)
    int kt = t & 15;      // k lane 0..15
    int e0 = et * 4;
    float acc[4][8] = {};
    for (int j = 0; j < 64; ++j) {
        float efr[4];
#pragma unroll
        for (int i = 0; i < 4; ++i) efr[i] = eft[e0 + i][j];   // 16-lane bcast
#pragma unroll
        for (int m = 0; m < 8; ++m) {
            float w = wt[m * 16 + kt][j];   // 16 distinct banks, 4-lane bcast
#pragma unroll
            for (int i = 0; i < 4; ++i)
                acc[i][m] += efr[i] * w;
        }
    }
#pragma unroll
    for (int i = 0; i < 4; ++i) {
        int e = eb + e0 + i;
        int s = src[e], d = dst[e];
        float4 exv = *(const float4*)(ex + (size_t)e * 4);
        float4 dnv = *(const float4*)(denom + (size_t)d * 4);
        float al[4] = {exv.x / dnv.x, exv.y / dnv.y, exv.z / dnv.z, exv.w / dnv.w};
        const float* pr = P + (size_t)s * F;
        float* hr = hne + (size_t)d * F;
#pragma unroll
        for (int m = 0; m < 8; ++m) {
            int k = m * 16 + kt;
            float mv = al[k >> 5] * (pr[k] + acc[i][m]);
            atomicAdd(&hr[k], mv);
        }
    }
}

// ---------------------------------------------------------------------------
// K4: h = relu((hne + nf) @ Wout.T + b); out = LN(h) * gamma + beta
// same GEMM structure as K1 + fused layernorm (8 lanes per node)
// ---------------------------------------------------------------------------
__global__ __launch_bounds__(256, 2) void k_node_out(
    const float* __restrict__ hne, const float* __restrict__ nf,
    const float* __restrict__ Wo, const float* __restrict__ bo,
    const float* __restrict__ gamma, const float* __restrict__ beta,
    float* __restrict__ out) {
    __shared__ float in_t[32][129];
    __shared__ float w_t[64][129];
    __shared__ float h_t[32][132];
    int t = threadIdx.x;
    int nb = blockIdx.x * 32;
#pragma unroll
    for (int i = 0; i < 4; ++i) {
        int f4 = i * 256 + t;
        int row = f4 >> 5, c4 = f4 & 31;
        float4 a = ((const float4*)(hne + (size_t)(nb + row) * F))[c4];
        float4 b = ((const float4*)(nf + (size_t)(nb + row) * F))[c4];
        in_t[row][c4 * 4 + 0] = a.x + b.x; in_t[row][c4 * 4 + 1] = a.y + b.y;
        in_t[row][c4 * 4 + 2] = a.z + b.z; in_t[row][c4 * 4 + 3] = a.w + b.w;
    }
    int kk = t & 63, ng = t >> 6;
    for (int kh = 0; kh < 2; ++kh) {
        __syncthreads();
#pragma unroll
        for (int i = 0; i < 8; ++i) {
            int f4 = i * 256 + t;
            int row = f4 >> 5, c4 = f4 & 31;
            float4 v = ((const float4*)(Wo + (size_t)(kh * 64 + row) * F))[c4];
            w_t[row][c4 * 4 + 0] = v.x; w_t[row][c4 * 4 + 1] = v.y;
            w_t[row][c4 * 4 + 2] = v.z; w_t[row][c4 * 4 + 3] = v.w;
        }
        __syncthreads();
        float acc[8] = {0.f, 0.f, 0.f, 0.f, 0.f, 0.f, 0.f, 0.f};
        for (int j = 0; j < 128; ++j) {
            float w = w_t[kk][j];
#pragma unroll
            for (int i = 0; i < 8; ++i)
                acc[i] += in_t[ng * 8 + i][j] * w;
        }
        float b = bo[kh * 64 + kk];
#pragma unroll
        for (int i = 0; i < 8; ++i) {
            float v = acc[i] + b;
            h_t[ng * 8 + i][kh * 64 + kk] = v > 0.f ? v : 0.f;
        }
    }
    __syncthreads();
    // layernorm: 8 lanes per node (nodes stay within a wave)
    int n = t >> 3, li = t & 7;
    float s = 0.f, ss = 0.f;
    float vals[16];
#pragma unroll
    for (int q = 0; q < 16; ++q) {
        float v = h_t[n][li * 16 + q];
        vals[q] = v; s += v; ss += v * v;
    }
#pragma unroll
    for (int o = 1; o < 8; o <<= 1) {
        s += __shfl_xor(s, o, 64);
        ss += __shfl_xor(ss, o, 64);
    }
    float mu = s * (1.f / 128.f);
    float var = ss * (1.f / 128.f) - mu * mu;
    float rstd = rsqrtf(var + 1e-5f);
    float* orow = out + (size_t)(nb + n) * F + li * 16;
#pragma unroll
    for (int q4 = 0; q4 < 4; ++q4) {
        float4 o;
        int k = li * 16 + q4 * 4;
        o.x = (vals[q4 * 4 + 0] - mu) * rstd * gamma[k + 0] + beta[k + 0];
        o.y = (vals[q4 * 4 + 1] - mu) * rstd * gamma[k + 1] + beta[k + 1];
        o.z = (vals[q4 * 4 + 2] - mu) * rstd * gamma[k + 2] + beta[k + 2];
        o.w = (vals[q4 * 4 + 3] - mu) * rstd * gamma[k + 3] + beta[k + 3];
        *(float4*)(orow + q4 * 4) = o;
    }
}

// ---------------------------------------------------------------------------
extern "C" void kernel_launch(void* const* d_in, const int* in_sizes, int n_in,
                              void* d_out, int out_size, void* d_ws, size_t ws_size,
                              hipStream_t stream) {
    const float* nf    = (const float*)d_in[0];
    const float* ef    = (const float*)d_in[1];
    const int*   src   = (const int*)d_in[2];
    const int*   dst   = (const int*)d_in[3];
    const float* Wp    = (const float*)d_in[4];
    const float* bp    = (const float*)d_in[5];
    const float* av    = (const float*)d_in[6];
    const float* Wo    = (const float*)d_in[7];
    const float* bo    = (const float*)d_in[8];
    const float* gamma = (const float*)d_in[9];
    const float* beta  = (const float*)d_in[10];
    float* out = (float*)d_out;

    float* P     = (float*)d_ws;                  // NN*128
    float* sn    = P + (size_t)NN * F;            // NN*4
    float* c     = sn + (size_t)NN * 4;           // 256
    float* denom = c + 256;                       // NN*4
    float* ex    = denom + (size_t)NN * 4;        // NE*4
    float* hne   = ex + (size_t)NE * 4;           // NN*128

    hipMemsetAsync(denom, 0, (size_t)NN * 4 * sizeof(float), stream);
    hipMemsetAsync(hne, 0, (size_t)NN * F * sizeof(float), stream);

    k_prep_c<<<1, 256, 0, stream>>>(Wp, av, c);
    k_node_proj<<<NN / 32, 256, 0, stream>>>(nf, Wp, bp, P);
    k_sn<<<(NN + 63) / 64, 256, 0, stream>>>(P, av, sn);
    k_edge_score<<<NE / 256, 256, 0, stream>>>(ef, src, dst, sn, c, ex, denom);
    k_edge_msg<<<NE / 64, 256, 0, stream>>>(ef, src, dst, Wp, P, ex, denom, hne);
    k_node_out<<<NN / 32, 256, 0, stream>>>(hne, nf, Wo, bo, gamma, beta, out);
}